// Round 9
// baseline (37.108 us; speedup 1.0000x reference)
//
#include <hip/hip_runtime.h>
#include <math.h>

#define DIM     1024
#define NSTAGES 10
#define HALFD   512                   // angles per stage = DIM/2
#define TABN    (NSTAGES * HALFD)     // 5120 floats per table

// ---------------------------------------------------------------------------
// Prep: cos/sin tables into workspace. ws layout: cos[10][512] | sin[10][512]
// ---------------------------------------------------------------------------
__global__ void bf_prep(const float* __restrict__ ang, float* __restrict__ ws) {
    int i = blockIdx.x * blockDim.x + threadIdx.x;
    if (i < TABN) {
        float s, c;
        sincosf(ang[i], &s, &c);
        ws[i]        = c;
        ws[TABN + i] = s;
    }
}

// ---------------------------------------------------------------------------
// Cross-lane xor exchange, cheapest pipe per mask:
//   m=1,2  : DPP quad_perm                 (VALU)
//   m=4,8  : ds_swizzle BitMode xor        (DS, imm pattern, no addr VGPR)
//   m=16,32: v_permlane{16,32}_swap_b32    (VALU! pair-trick, see below)
// ---------------------------------------------------------------------------
__device__ __forceinline__ float xor1(float f) {   // quad_perm [1,0,3,2]
    return __builtin_bit_cast(float,
        __builtin_amdgcn_update_dpp(0, __builtin_bit_cast(int, f), 0xB1, 0xF, 0xF, true));
}
__device__ __forceinline__ float xor2(float f) {   // quad_perm [2,3,0,1]
    return __builtin_bit_cast(float,
        __builtin_amdgcn_update_dpp(0, __builtin_bit_cast(int, f), 0x4E, 0xF, 0xF, true));
}
__device__ __forceinline__ float xor4(float f) {
    return __builtin_bit_cast(float,
        __builtin_amdgcn_ds_swizzle(__builtin_bit_cast(int, f), 0x101F));
}
__device__ __forceinline__ float xor8(float f) {
    return __builtin_bit_cast(float,
        __builtin_amdgcn_ds_swizzle(__builtin_bit_cast(int, f), 0x201F));
}

// half-swap primitives: a.hi-block <-> b.lo-block (both regs modified)
__device__ __forceinline__ void pl16(float& a, float& b) {
    asm("v_permlane16_swap_b32 %0, %1" : "+v"(a), "+v"(b));
}
__device__ __forceinline__ void pl32(float& a, float& b) {
    asm("v_permlane32_swap_b32 %0, %1" : "+v"(a), "+v"(b));
}

// one cross-lane stage S (2..5) applied to a 2-row batch via value-exchange
#define XSTAGE(S, XORF)                                                    \
    {                                                                      \
        constexpr int m = 1 << ((S) - 2);                                  \
        const float* cT = cosT + (S) * HALFD;                              \
        const float* sT = sinT + (S) * HALFD;                              \
        const int l0 = lane & ~m;                                          \
        const float sgn = (lane & m) ? -1.0f : 1.0f;                       \
        _Pragma("unroll")                                                  \
        for (int c = 0; c < 4; ++c) {                                      \
            const int p0 = (((c << (7 - (S))) + (l0 >> ((S) - 1))) << (S)) \
                         + 4 * (l0 & (m - 1));                             \
            float4 C = *(const float4*)&cT[p0];                            \
            float4 Sv = *(const float4*)&sT[p0];                           \
            Sv.x *= sgn; Sv.y *= sgn; Sv.z *= sgn; Sv.w *= sgn;            \
            _Pragma("unroll")                                              \
            for (int r = 0; r < 2; ++r) {                                  \
                float4 u = v[r][c];                                        \
                float tx = XORF(u.x), ty = XORF(u.y);                      \
                float tz = XORF(u.z), tw = XORF(u.w);                      \
                v[r][c].x = C.x * u.x + Sv.x * tx;                         \
                v[r][c].y = C.y * u.y + Sv.y * ty;                         \
                v[r][c].z = C.z * u.z + Sv.z * tz;                         \
                v[r][c].w = C.w * u.w + Sv.w * tw;                         \
            }                                                              \
        }                                                                  \
    }

// permlane pair-trick: A,B = same component of row0/row1 (same C,S for all
// lanes: pair (l, l^m) shares the table entry since p0 uses l0 = lane&~m).
// swap -> each lane holds (left,right) of one row's pair; rotate locally;
// swap back (involution) restores positions.
#define PLPAIR(A, B, Cv, Svv, PLFN)                                        \
    {                                                                      \
        float a_ = (A), b_ = (B);                                          \
        PLFN(a_, b_);                 /* a_ = lefts, b_ = rights */        \
        float an_ = Cv * a_ + Svv * b_;   /* left'  */                     \
        float bn_ = Cv * b_ - Svv * a_;   /* right' */                     \
        PLFN(an_, bn_);                                                    \
        (A) = an_; (B) = bn_;                                              \
    }

#define XSTAGE_PL(S, PLFN)                                                 \
    {                                                                      \
        constexpr int m = 1 << ((S) - 2);                                  \
        const float* cT = cosT + (S) * HALFD;                              \
        const float* sT = sinT + (S) * HALFD;                              \
        const int l0 = lane & ~m;                                          \
        _Pragma("unroll")                                                  \
        for (int c = 0; c < 4; ++c) {                                      \
            const int p0 = (((c << (7 - (S))) + (l0 >> ((S) - 1))) << (S)) \
                         + 4 * (l0 & (m - 1));                             \
            float4 C = *(const float4*)&cT[p0];                            \
            float4 Sv = *(const float4*)&sT[p0];                           \
            PLPAIR(v[0][c].x, v[1][c].x, C.x, Sv.x, PLFN)                  \
            PLPAIR(v[0][c].y, v[1][c].y, C.y, Sv.y, PLFN)                  \
            PLPAIR(v[0][c].z, v[1][c].z, C.z, Sv.z, PLFN)                  \
            PLPAIR(v[0][c].w, v[1][c].w, C.w, Sv.w, PLFN)                  \
        }                                                                  \
    }

// ---------------------------------------------------------------------------
// Process one 2-row batch through all 10 stages (register working set:
// 32 data VGPRs + ~16 table/temp -> the proven no-spill size from R1/R5/R8).
// ---------------------------------------------------------------------------
__device__ __forceinline__ void processBatch(float4 (&v)[2][4],
                                             const float* __restrict__ cosT,
                                             const float* __restrict__ sinT,
                                             int lane)
{
    // ---- stages 0,1: intra-float4. p = 128c + 2*lane + {0,1} -------------
    #pragma unroll
    for (int s01 = 0; s01 < 2; ++s01) {
        const float* cT = cosT + s01 * HALFD;
        const float* sT = sinT + s01 * HALFD;
        #pragma unroll
        for (int c = 0; c < 4; ++c) {
            const int p = 128 * c + 2 * lane;
            float2 cc = *(const float2*)&cT[p];
            float2 ss = *(const float2*)&sT[p];
            #pragma unroll
            for (int r = 0; r < 2; ++r) {
                float4 u = v[r][c];
                if (s01 == 0) {
                    v[r][c].x = cc.x * u.x + ss.x * u.y;
                    v[r][c].y = cc.x * u.y - ss.x * u.x;
                    v[r][c].z = cc.y * u.z + ss.y * u.w;
                    v[r][c].w = cc.y * u.w - ss.y * u.z;
                } else {
                    v[r][c].x = cc.x * u.x + ss.x * u.z;
                    v[r][c].z = cc.x * u.z - ss.x * u.x;
                    v[r][c].y = cc.y * u.y + ss.y * u.w;
                    v[r][c].w = cc.y * u.w - ss.y * u.y;
                }
            }
        }
    }

    // ---- stages 2..7: cross-lane exchanges -------------------------------
    XSTAGE(2, xor1)
    XSTAGE(3, xor2)
    XSTAGE(4, xor4)
    XSTAGE(5, xor8)
    XSTAGE_PL(6, pl16)
    XSTAGE_PL(7, pl32)

    // ---- stage 8: pairs (c0,c1),(c2,c3); p = 256*g + 4*lane + d ----------
    {
        const float* cT = cosT + 8 * HALFD;
        const float* sT = sinT + 8 * HALFD;
        #pragma unroll
        for (int g = 0; g < 2; ++g) {
            const int p0 = 256 * g + 4 * lane;
            float4 C = *(const float4*)&cT[p0];
            float4 S = *(const float4*)&sT[p0];
            #pragma unroll
            for (int r = 0; r < 2; ++r) {
                float4 L = v[r][2 * g], Rr = v[r][2 * g + 1];
                v[r][2 * g].x     = C.x * L.x + S.x * Rr.x;
                v[r][2 * g].y     = C.y * L.y + S.y * Rr.y;
                v[r][2 * g].z     = C.z * L.z + S.z * Rr.z;
                v[r][2 * g].w     = C.w * L.w + S.w * Rr.w;
                v[r][2 * g + 1].x = C.x * Rr.x - S.x * L.x;
                v[r][2 * g + 1].y = C.y * Rr.y - S.y * L.y;
                v[r][2 * g + 1].z = C.z * Rr.z - S.z * L.z;
                v[r][2 * g + 1].w = C.w * Rr.w - S.w * L.w;
            }
        }
    }

    // ---- stage 9: pairs (c0,c2),(c1,c3) ----------------------------------
    {
        const float* cT = cosT + 9 * HALFD;
        const float* sT = sinT + 9 * HALFD;
        #pragma unroll
        for (int g = 0; g < 2; ++g) {
            const int p0 = 256 * g + 4 * lane;
            float4 C = *(const float4*)&cT[p0];
            float4 S = *(const float4*)&sT[p0];
            #pragma unroll
            for (int r = 0; r < 2; ++r) {
                float4 L = v[r][g], Rr = v[r][g + 2];
                v[r][g].x     = C.x * L.x + S.x * Rr.x;
                v[r][g].y     = C.y * L.y + S.y * Rr.y;
                v[r][g].z     = C.z * L.z + S.z * Rr.z;
                v[r][g].w     = C.w * L.w + S.w * Rr.w;
                v[r][g + 2].x = C.x * Rr.x - S.x * L.x;
                v[r][g + 2].y = C.y * Rr.y - S.y * L.y;
                v[r][g + 2].z = C.z * Rr.z - S.z * L.z;
                v[r][g + 2].w = C.w * Rr.w - S.w * L.w;
            }
        }
    }
}

// ---------------------------------------------------------------------------
// Main: 1024 blocks x 4 waves, 4 rows/wave as TWO explicit 2-row batches
// with separate local arrays + a compiler fence between them (R8's proven
// no-spill skeleton, unchanged). LDS table. Whole grid resident:
// 1024 blocks / 4 per CU (40KB LDS) = 256 CUs, one dispatch round.
// ---------------------------------------------------------------------------
__global__ __launch_bounds__(256) void bf_main(
    const float* __restrict__ x,
    const float* __restrict__ tab,
    float* __restrict__ out)
{
    __shared__ __align__(16) float cosT[TABN];
    __shared__ __align__(16) float sinT[TABN];
    const int tid  = threadIdx.x;
    const int lane = tid & 63;
    const int gwid = blockIdx.x * 4 + (tid >> 6);   // global wave id, 4 rows each

    // ---- stage table into LDS (10 float4 loads/thread, issued first) -----
    {
        const float4* s4 = (const float4*)tab;
        float4* c4 = (float4*)cosT;
        float4* n4 = (float4*)sinT;
        #pragma unroll
        for (int i = 0; i < TABN / 4 / 256; ++i) {   // 5 iterations
            const int idx = i * 256 + tid;
            c4[idx] = s4[idx];
            n4[idx] = s4[TABN / 4 + idx];
        }
    }

    const float4* xp = (const float4*)x   + (size_t)gwid * 4 * (DIM / 4) + lane;
    float4*       op = (float4*)      out + (size_t)gwid * 4 * (DIM / 4) + lane;

    // ---- batch 0: loads issued BEFORE the barrier (hidden under staging) --
    float4 v0[2][4];
    #pragma unroll
    for (int r = 0; r < 2; ++r)
        #pragma unroll
        for (int c = 0; c < 4; ++c)
            v0[r][c] = xp[r * 256 + c * 64];

    __syncthreads();

    {
        float4 (&v)[2][4] = v0;   // alias so XSTAGE sees `v`
        processBatch(v, cosT, sinT, lane);
    }
    #pragma unroll
    for (int r = 0; r < 2; ++r)
        #pragma unroll
        for (int c = 0; c < 4; ++c)
            op[r * 256 + c * 64] = v0[r][c];

    asm volatile("" ::: "memory");   // fence: no cross-batch hoist/CSE

    // ---- batch 1 ----------------------------------------------------------
    float4 v1[2][4];
    #pragma unroll
    for (int r = 0; r < 2; ++r)
        #pragma unroll
        for (int c = 0; c < 4; ++c)
            v1[r][c] = xp[(2 + r) * 256 + c * 64];

    {
        float4 (&v)[2][4] = v1;
        processBatch(v, cosT, sinT, lane);
    }
    #pragma unroll
    for (int r = 0; r < 2; ++r)
        #pragma unroll
        for (int c = 0; c < 4; ++c)
            op[(2 + r) * 256 + c * 64] = v1[r][c];
}

extern "C" void kernel_launch(void* const* d_in, const int* in_sizes, int n_in,
                              void* d_out, int out_size, void* d_ws, size_t ws_size,
                              hipStream_t stream) {
    const float* x   = (const float*)d_in[0];
    const float* ang = (const float*)d_in[1];
    float* out = (float*)d_out;

    const int nrows = out_size / DIM;          // 16384
    // 4 waves/block x 4 rows/wave = 16 rows/block -> 1024 blocks,
    // 4 blocks/CU at 40KB LDS -> whole grid resident in one round.
    const int nblocks = nrows / 16;

    float* tab = (float*)d_ws;                 // 40 KB
    bf_prep<<<(TABN + 255) / 256, 256, 0, stream>>>(ang, tab);
    bf_main<<<nblocks, 256, 0, stream>>>(x, tab, out);
}

// Round 10
// 31.869 us; speedup vs baseline: 1.1644x; 1.1644x over previous
//
#include <hip/hip_runtime.h>
#include <math.h>

#define DIM     1024
#define NSTAGES 10
#define HALFD   512                   // angles per stage = DIM/2
#define TABN    (NSTAGES * HALFD)     // 5120 floats per table

// ---------------------------------------------------------------------------
// Prep: cos/sin tables into workspace. ws layout: cos[10][512] | sin[10][512]
// ---------------------------------------------------------------------------
__global__ void bf_prep(const float* __restrict__ ang, float* __restrict__ ws) {
    int i = blockIdx.x * blockDim.x + threadIdx.x;
    if (i < TABN) {
        float s, c;
        sincosf(ang[i], &s, &c);
        ws[i]        = c;
        ws[TABN + i] = s;
    }
}

// ---------------------------------------------------------------------------
// Cross-lane xor exchange, cheapest pipe per mask:
//   m=1,2  : DPP quad_perm                 (VALU)
//   m=4,8  : ds_swizzle BitMode xor        (DS, imm pattern, no addr VGPR)
//   m=16,32: v_permlane{16,32}_swap_b32    (VALU crossbar) via INTRA-ROW
//            component pairing (x,y)/(z,w) -- rows stay independent (the
//            R9 regression came from pairing row0/row1, serializing them).
// ---------------------------------------------------------------------------
__device__ __forceinline__ float xor1(float f) {   // quad_perm [1,0,3,2]
    return __builtin_bit_cast(float,
        __builtin_amdgcn_update_dpp(0, __builtin_bit_cast(int, f), 0xB1, 0xF, 0xF, true));
}
__device__ __forceinline__ float xor2(float f) {   // quad_perm [2,3,0,1]
    return __builtin_bit_cast(float,
        __builtin_amdgcn_update_dpp(0, __builtin_bit_cast(int, f), 0x4E, 0xF, 0xF, true));
}
__device__ __forceinline__ float xor4(float f) {
    return __builtin_bit_cast(float,
        __builtin_amdgcn_ds_swizzle(__builtin_bit_cast(int, f), 0x101F));
}
__device__ __forceinline__ float xor8(float f) {
    return __builtin_bit_cast(float,
        __builtin_amdgcn_ds_swizzle(__builtin_bit_cast(int, f), 0x201F));
}

// half-swap primitives: exchange a's hi-group with b's lo-group (both regs)
__device__ __forceinline__ void pl16(float& a, float& b) {
    asm("v_permlane16_swap_b32 %0, %1" : "+v"(a), "+v"(b));
}
__device__ __forceinline__ void pl32(float& a, float& b) {
    asm("v_permlane32_swap_b32 %0, %1" : "+v"(a), "+v"(b));
}

// one cross-lane stage S (2..5) applied to a 2-row batch via value-exchange
#define XSTAGE(S, XORF)                                                    \
    {                                                                      \
        constexpr int m = 1 << ((S) - 2);                                  \
        const float* cT = cosT + (S) * HALFD;                              \
        const float* sT = sinT + (S) * HALFD;                              \
        const int l0 = lane & ~m;                                          \
        const float sgn = (lane & m) ? -1.0f : 1.0f;                       \
        _Pragma("unroll")                                                  \
        for (int c = 0; c < 4; ++c) {                                      \
            const int p0 = (((c << (7 - (S))) + (l0 >> ((S) - 1))) << (S)) \
                         + 4 * (l0 & (m - 1));                             \
            float4 C = *(const float4*)&cT[p0];                            \
            float4 Sv = *(const float4*)&sT[p0];                           \
            Sv.x *= sgn; Sv.y *= sgn; Sv.z *= sgn; Sv.w *= sgn;            \
            _Pragma("unroll")                                              \
            for (int r = 0; r < 2; ++r) {                                  \
                float4 u = v[r][c];                                        \
                float tx = XORF(u.x), ty = XORF(u.y);                      \
                float tz = XORF(u.z), tw = XORF(u.w);                      \
                v[r][c].x = C.x * u.x + Sv.x * tx;                         \
                v[r][c].y = C.y * u.y + Sv.y * ty;                         \
                v[r][c].z = C.z * u.z + Sv.z * tz;                         \
                v[r][c].w = C.w * u.w + Sv.w * tw;                         \
            }                                                              \
        }                                                                  \
    }

// permlane pair-trick on two SAME-ROW components A,B:
// after PLFN(a,b): lo-group lanes hold (A[l], A[l^m]) = A's (left,right);
// hi-group lanes hold (B[l^m], B[l]) = B's (left,right). Each lane rotates
// ONE pair with its own-selected multiplier; swap back restores layout.
#define PLPAIR(A, B, Cv, Svv, PLFN)                                        \
    {                                                                      \
        float a_ = (A), b_ = (B);                                          \
        PLFN(a_, b_);                                                      \
        float an_ = Cv * a_ + Svv * b_;   /* left'  */                     \
        float bn_ = Cv * b_ - Svv * a_;   /* right' */                     \
        PLFN(an_, bn_);                                                    \
        (A) = an_; (B) = bn_;                                              \
    }

// stage S in {6,7}: lanes with (lane&SELBIT)==0 compute the A-component's
// pair (needs C.x/S.x resp C.z/S.z); hi lanes compute B's (C.y/S.y, C.w/S.w)
#define XSTAGE_PL(S, PLFN, SELBIT)                                         \
    {                                                                      \
        constexpr int m = 1 << ((S) - 2);                                  \
        const float* cT = cosT + (S) * HALFD;                              \
        const float* sT = sinT + (S) * HALFD;                              \
        const int l0 = lane & ~m;                                          \
        const bool hi = (lane & (SELBIT)) != 0;                            \
        _Pragma("unroll")                                                  \
        for (int c = 0; c < 4; ++c) {                                      \
            const int p0 = (((c << (7 - (S))) + (l0 >> ((S) - 1))) << (S)) \
                         + 4 * (l0 & (m - 1));                             \
            float4 C = *(const float4*)&cT[p0];                            \
            float4 Sv = *(const float4*)&sT[p0];                           \
            float cxy = hi ? C.y : C.x,  sxy = hi ? Sv.y : Sv.x;           \
            float czw = hi ? C.w : C.z,  szw = hi ? Sv.w : Sv.z;           \
            _Pragma("unroll")                                              \
            for (int r = 0; r < 2; ++r) {                                  \
                PLPAIR(v[r][c].x, v[r][c].y, cxy, sxy, PLFN)               \
                PLPAIR(v[r][c].z, v[r][c].w, czw, szw, PLFN)               \
            }                                                              \
        }                                                                  \
    }

// ---------------------------------------------------------------------------
// Process one 2-row batch through all 10 stages (register working set:
// 32 data VGPRs + ~16 table/temp -> the proven no-spill size from R1/R5/R8).
// ---------------------------------------------------------------------------
__device__ __forceinline__ void processBatch(float4 (&v)[2][4],
                                             const float* __restrict__ cosT,
                                             const float* __restrict__ sinT,
                                             int lane)
{
    // ---- stages 0,1: intra-float4. p = 128c + 2*lane + {0,1} -------------
    #pragma unroll
    for (int s01 = 0; s01 < 2; ++s01) {
        const float* cT = cosT + s01 * HALFD;
        const float* sT = sinT + s01 * HALFD;
        #pragma unroll
        for (int c = 0; c < 4; ++c) {
            const int p = 128 * c + 2 * lane;
            float2 cc = *(const float2*)&cT[p];
            float2 ss = *(const float2*)&sT[p];
            #pragma unroll
            for (int r = 0; r < 2; ++r) {
                float4 u = v[r][c];
                if (s01 == 0) {
                    v[r][c].x = cc.x * u.x + ss.x * u.y;
                    v[r][c].y = cc.x * u.y - ss.x * u.x;
                    v[r][c].z = cc.y * u.z + ss.y * u.w;
                    v[r][c].w = cc.y * u.w - ss.y * u.z;
                } else {
                    v[r][c].x = cc.x * u.x + ss.x * u.z;
                    v[r][c].z = cc.x * u.z - ss.x * u.x;
                    v[r][c].y = cc.y * u.y + ss.y * u.w;
                    v[r][c].w = cc.y * u.w - ss.y * u.y;
                }
            }
        }
    }

    // ---- stages 2..7: cross-lane exchanges -------------------------------
    XSTAGE(2, xor1)
    XSTAGE(3, xor2)
    XSTAGE(4, xor4)
    XSTAGE(5, xor8)
    XSTAGE_PL(6, pl16, 16)
    XSTAGE_PL(7, pl32, 32)

    // ---- stage 8: pairs (c0,c1),(c2,c3); p = 256*g + 4*lane + d ----------
    {
        const float* cT = cosT + 8 * HALFD;
        const float* sT = sinT + 8 * HALFD;
        #pragma unroll
        for (int g = 0; g < 2; ++g) {
            const int p0 = 256 * g + 4 * lane;
            float4 C = *(const float4*)&cT[p0];
            float4 S = *(const float4*)&sT[p0];
            #pragma unroll
            for (int r = 0; r < 2; ++r) {
                float4 L = v[r][2 * g], Rr = v[r][2 * g + 1];
                v[r][2 * g].x     = C.x * L.x + S.x * Rr.x;
                v[r][2 * g].y     = C.y * L.y + S.y * Rr.y;
                v[r][2 * g].z     = C.z * L.z + S.z * Rr.z;
                v[r][2 * g].w     = C.w * L.w + S.w * Rr.w;
                v[r][2 * g + 1].x = C.x * Rr.x - S.x * L.x;
                v[r][2 * g + 1].y = C.y * Rr.y - S.y * L.y;
                v[r][2 * g + 1].z = C.z * Rr.z - S.z * L.z;
                v[r][2 * g + 1].w = C.w * Rr.w - S.w * L.w;
            }
        }
    }

    // ---- stage 9: pairs (c0,c2),(c1,c3) ----------------------------------
    {
        const float* cT = cosT + 9 * HALFD;
        const float* sT = sinT + 9 * HALFD;
        #pragma unroll
        for (int g = 0; g < 2; ++g) {
            const int p0 = 256 * g + 4 * lane;
            float4 C = *(const float4*)&cT[p0];
            float4 S = *(const float4*)&sT[p0];
            #pragma unroll
            for (int r = 0; r < 2; ++r) {
                float4 L = v[r][g], Rr = v[r][g + 2];
                v[r][g].x     = C.x * L.x + S.x * Rr.x;
                v[r][g].y     = C.y * L.y + S.y * Rr.y;
                v[r][g].z     = C.z * L.z + S.z * Rr.z;
                v[r][g].w     = C.w * L.w + S.w * Rr.w;
                v[r][g + 2].x = C.x * Rr.x - S.x * L.x;
                v[r][g + 2].y = C.y * Rr.y - S.y * L.y;
                v[r][g + 2].z = C.z * Rr.z - S.z * L.z;
                v[r][g + 2].w = C.w * Rr.w - S.w * L.w;
            }
        }
    }
}

// ---------------------------------------------------------------------------
// Main: 1024 blocks x 4 waves, 4 rows/wave as TWO explicit 2-row batches
// with separate local arrays + a compiler fence between them (R8's proven
// no-spill skeleton, unchanged). LDS table. Whole grid resident:
// 1024 blocks / 4 per CU (40KB LDS) = 256 CUs, one dispatch round.
// ---------------------------------------------------------------------------
__global__ __launch_bounds__(256) void bf_main(
    const float* __restrict__ x,
    const float* __restrict__ tab,
    float* __restrict__ out)
{
    __shared__ __align__(16) float cosT[TABN];
    __shared__ __align__(16) float sinT[TABN];
    const int tid  = threadIdx.x;
    const int lane = tid & 63;
    const int gwid = blockIdx.x * 4 + (tid >> 6);   // global wave id, 4 rows each

    // ---- stage table into LDS (10 float4 loads/thread, issued first) -----
    {
        const float4* s4 = (const float4*)tab;
        float4* c4 = (float4*)cosT;
        float4* n4 = (float4*)sinT;
        #pragma unroll
        for (int i = 0; i < TABN / 4 / 256; ++i) {   // 5 iterations
            const int idx = i * 256 + tid;
            c4[idx] = s4[idx];
            n4[idx] = s4[TABN / 4 + idx];
        }
    }

    const float4* xp = (const float4*)x   + (size_t)gwid * 4 * (DIM / 4) + lane;
    float4*       op = (float4*)      out + (size_t)gwid * 4 * (DIM / 4) + lane;

    // ---- batch 0: loads issued BEFORE the barrier (hidden under staging) --
    float4 v0[2][4];
    #pragma unroll
    for (int r = 0; r < 2; ++r)
        #pragma unroll
        for (int c = 0; c < 4; ++c)
            v0[r][c] = xp[r * 256 + c * 64];

    __syncthreads();

    {
        float4 (&v)[2][4] = v0;   // alias so XSTAGE sees `v`
        processBatch(v, cosT, sinT, lane);
    }
    #pragma unroll
    for (int r = 0; r < 2; ++r)
        #pragma unroll
        for (int c = 0; c < 4; ++c)
            op[r * 256 + c * 64] = v0[r][c];

    asm volatile("" ::: "memory");   // fence: no cross-batch hoist/CSE

    // ---- batch 1 ----------------------------------------------------------
    float4 v1[2][4];
    #pragma unroll
    for (int r = 0; r < 2; ++r)
        #pragma unroll
        for (int c = 0; c < 4; ++c)
            v1[r][c] = xp[(2 + r) * 256 + c * 64];

    {
        float4 (&v)[2][4] = v1;
        processBatch(v, cosT, sinT, lane);
    }
    #pragma unroll
    for (int r = 0; r < 2; ++r)
        #pragma unroll
        for (int c = 0; c < 4; ++c)
            op[(2 + r) * 256 + c * 64] = v1[r][c];
}

extern "C" void kernel_launch(void* const* d_in, const int* in_sizes, int n_in,
                              void* d_out, int out_size, void* d_ws, size_t ws_size,
                              hipStream_t stream) {
    const float* x   = (const float*)d_in[0];
    const float* ang = (const float*)d_in[1];
    float* out = (float*)d_out;

    const int nrows = out_size / DIM;          // 16384
    // 4 waves/block x 4 rows/wave = 16 rows/block -> 1024 blocks,
    // 4 blocks/CU at 40KB LDS -> whole grid resident in one round.
    const int nblocks = nrows / 16;

    float* tab = (float*)d_ws;                 // 40 KB
    bf_prep<<<(TABN + 255) / 256, 256, 0, stream>>>(ang, tab);
    bf_main<<<nblocks, 256, 0, stream>>>(x, tab, out);
}